// Round 7
// baseline (3237.063 us; speedup 1.0000x reference)
//
#include <hip/hip_runtime.h>

typedef __attribute__((ext_vector_type(8))) short short8;
typedef __attribute__((ext_vector_type(4))) float floatx4;
typedef __attribute__((ext_vector_type(4))) unsigned short ushort4v;

#define DEV __device__ __forceinline__

constexpr int M_TOT = 6272;   // 8 * 784 output positions
constexpr int MAXB  = 196;    // blocks per XCD bin = 1568/8 EXACTLY (R7 fix:
                              // capacity-constrained binning, nothing dropped)

DEV void async_ld16(const void* g, void* l) {
  __builtin_amdgcn_global_load_lds(
      (const __attribute__((address_space(1))) unsigned int*)g,
      (__attribute__((address_space(3))) unsigned int*)l,
      16, 0, 0);
}

DEV unsigned short f2bf(float x) {
  union { float f; unsigned int u; } v; v.f = x;
  unsigned int u = v.u;
  u += 0x7FFFu + ((u >> 16) & 1u);   // round-to-nearest-even
  return (unsigned short)(u >> 16);
}

DEV float bf2f(unsigned short s) {
  union { unsigned int u; float f; } v; v.u = ((unsigned int)s) << 16;
  return v.f;
}

// ---------------------------------------------------------------------------
// Device-side schedule builder. For each conv: 1568 cells = 49 x-tiles * 32 g
// (g = n*S + z), walked x-major; work-prefix target bin, CAPACITY-CONSTRAINED
// to 196 cells/bin with nearest-non-full probing (R6 dropped overflow cells ->
// poisoned partials -> absmax 0.94; total capacity == cell count guarantees a
// bijection now). x-contiguous slabs keep R4's L2 locality + R5's balance.
// tab[b*MAXB + i] = cell. Single lane, ~10k ops.
// ---------------------------------------------------------------------------
__global__ void make_sched(unsigned short* __restrict__ tab1,
                           unsigned short* __restrict__ tab2) {
  if (threadIdx.x != 0) return;
  for (int conv = 0; conv < 2; ++conv) {
    const int S = conv ? 8 : 4;
    unsigned short* tab = conv ? tab2 : tab1;
    long total = 0;
    int w[1568];
    for (int x = 0; x < 49; ++x) {
      const int m0 = x * 128;
      const int c1 = m0 / 196, c2 = (m0 + 127) / 196;
      bool kdv[3];
      for (int kd = 0; kd < 3; ++kd) {
        bool v = false;
        for (int ci = 0; ci < 2; ++ci) {
          int c = ci ? c2 : c1;
          if (ci && c2 == c1) continue;
          int t = c >> 2, d = c & 3, s = d + kd;
          bool ok = (s >= 1) && (s <= 4);
          if (conv == 0) ok = ok && (s >= 5 - t);   // conv1 frame condition
          v = v || ok;
        }
        kdv[kd] = v;
      }
      for (int g = 0; g < 32; ++g) {
        int z = g % S;
        int t0 = (27 * z) / S, t1 = (27 * (z + 1)) / S, cnt = 0;
        for (int tap = t0; tap < t1; ++tap) if (kdv[tap / 9]) ++cnt;
        w[x * 32 + g] = cnt * 16 + 3;   // 16 K-steps per tap + per-block overhead
        total += w[x * 32 + g];
      }
    }
    long cum = 0;
    int count[8] = {0, 0, 0, 0, 0, 0, 0, 0};
    for (int c = 0; c < 1568; ++c) {
      int b = (int)(((cum + w[c] / 2) * 8) / total);
      if (b > 7) b = 7;
      if (count[b] >= MAXB) {                 // capacity probe (R7 fix)
        int nb = -1;
        for (int d = b + 1; d < 8 && nb < 0; ++d) if (count[d] < MAXB) nb = d;
        for (int d = b - 1; d >= 0 && nb < 0; --d) if (count[d] < MAXB) nb = d;
        b = nb;                               // always found: capacity == cells
      }
      tab[b * MAXB + count[b]++] = (unsigned short)c;
      cum += w[c];
    }
  }
}

// ---------------------------------------------------------------------------
// Weight transform: conv_w fp32 [O][C][3][3][3] -> bf16 [tap][o][c]  (B^T).
// LDS transpose — coalesced reads and writes.
// ---------------------------------------------------------------------------
__global__ void wtrans(const float* __restrict__ w, unsigned short* __restrict__ wt,
                       int total /* = O*C, multiple of 256 */) {
  __shared__ unsigned short l[256 * 27];
  const int tid  = threadIdx.x;
  const int base = blockIdx.x * 256;
  #pragma unroll 1
  for (int j = tid; j < 256 * 27; j += 256)
    l[j] = f2bf(w[(size_t)base * 27 + j]);
  __syncthreads();
  #pragma unroll 1
  for (int tap = 0; tap < 27; ++tap)
    wt[(size_t)tap * total + base + tid] = l[tid * 27 + tap];
}

// ---------------------------------------------------------------------------
// Build P1: videos fp32 [8][1024][14][14] -> P1 bf16 [t=8][s=6][16][16][1024]
// P1[t][s][h+1][w+1][c] = videos[t-5+s][c][h][w] for s in 1..4 (else zero).
// ---------------------------------------------------------------------------
__global__ void build_P1(const float* __restrict__ videos, unsigned short* __restrict__ P1) {
  const int f  = blockIdx.x;
  const int c0 = blockIdx.y * 64;
  const int tid = threadIdx.x;
  __shared__ unsigned short tile[64][196];

  #pragma unroll 1
  for (int it = 0; it < 49; ++it) {       // 49*256 = 64*196 exactly
    int idx = it * 256 + tid;
    int c = idx / 196, r = idx - c * 196;
    tile[c][r] = f2bf(videos[(size_t)(f * 1024 + c0 + c) * 196 + r]);
  }
  __syncthreads();

  const int c   = tid & 63;
  const int hwq = tid >> 6;
  #pragma unroll 1
  for (int s = 1; s <= 4; ++s) {
    int t = f + 5 - s;
    if (t > 7) continue;
    unsigned short* dst = P1 + (size_t)(t * 6 + s) * 256 * 1024 + (size_t)c0;
    #pragma unroll 1
    for (int it = 0; it < 49; ++it) {
      int hw = it * 4 + hwq;
      int h = hw / 14, w = hw - h * 14;
      dst[(size_t)((h + 1) * 16 + (w + 1)) * 1024 + c] = tile[c][hw];
    }
  }
}

// ---------------------------------------------------------------------------
// Implicit-GEMM conv, split-K over taps. 128x128 tile, BK=64, global_load_lds
// x16 with XOR-swizzled segment fetch (zero LDS bank conflicts — R2),
// mfma_f32_16x16x32_bf16, structural tap skipping (R5, exact), schedule-table
// block mapping (R6/R7). Writes bf16 partial sums; slice z goes to part0
// (z<S/2) or alt0 (z>=S/2, a dead weight region — see kernel_launch ordering).
// A: padded input P [8][6][16][16][CIN] bf16;  B: Wt [27][COUT][CIN] bf16.
// Grid: 8*MAXB slots; slot -> tab[(slot&7)*MAXB + (slot>>3)] (all valid).
// ---------------------------------------------------------------------------
template <int CIN, int COUT, int SLICES, bool TCOND>
__global__ __launch_bounds__(256) void conv_gemm(
    const unsigned short* __restrict__ P,
    const unsigned short* __restrict__ Wt,
    const unsigned short* __restrict__ tab,
    unsigned short* __restrict__ part0,
    unsigned short* __restrict__ alt0)
{
  __shared__ short lA[128 * 64];
  __shared__ short lB[128 * 64];
  const int slot = blockIdx.x;
  const int cellv = tab[(slot & 7) * MAXB + (slot >> 3)];

  const int tid  = threadIdx.x;
  const int wave = tid >> 6;
  const int lane = tid & 63;

  const int x = cellv >> 5;              // 0..48
  const int g = cellv & 31;              // n*SLICES + z
  const int m0 = x * 128;
  const int n0 = (g / SLICES) * 128;
  const int z  = g % SLICES;

  const int tap0 = (27 * z) / SLICES;
  const int tap1 = (27 * (z + 1)) / SLICES;
  const size_t SS = (size_t)M_TOT * COUT;
  unsigned short* partOut = (z < SLICES / 2)
      ? part0 + (size_t)z * SS
      : alt0 + (size_t)(z - SLICES / 2) * SS;

  // Tile-level depth-tap validity (exact skip of all-zero slices).
  bool kdv[3];
  {
    const int c1 = m0 / 196, c2 = (m0 + 127) / 196;
    #pragma unroll
    for (int kd = 0; kd < 3; ++kd) {
      bool v = false;
      #pragma unroll
      for (int ci = 0; ci < 2; ++ci) {
        int c = ci ? c2 : c1;
        if (ci && c2 == c1) continue;
        int t = c >> 2, d = c & 3, s = d + kd;
        bool ok = (s >= 1) && (s <= 4);
        if (TCOND) ok = ok && (s >= 5 - t);
        v = v || ok;
      }
      kdv[kd] = v;
    }
  }

  // Staging: LDS segment s_i = i*256+tid (16B units); row r = s_i>>3.
  // XOR swizzle: fetch global segment (tid&7)^(r&7).
  const int rb   = tid >> 3;
  const int segb = (((tid & 7) ^ (rb & 7)) * 16);
  int aoff[4], boff[4];
  #pragma unroll
  for (int i = 0; i < 4; ++i) {
    int r = i * 32 + rb;
    int m = m0 + r;
    int t = m / 784;  int r2 = m - t * 784;
    int d = r2 / 196; int r3 = r2 - d * 196;
    int h = r3 / 14;  int w = r3 - h * 14;
    aoff[i] = ((((t * 6 + d) * 16 + h) * 16 + w) * CIN) * 2 + segb;  // tap-separable
    boff[i] = ((n0 + r) * CIN) * 2 + segb;
  }

  floatx4 acc[4][4];
  const floatx4 zero = {0.f, 0.f, 0.f, 0.f};
  #pragma unroll
  for (int i = 0; i < 4; ++i)
    #pragma unroll
    for (int j = 0; j < 4; ++j) acc[i][j] = zero;

  const char* Pb = (const char*)P;
  const char* Wb = (const char*)Wt;
  const int wm = (wave >> 1) * 64;
  const int wn = (wave & 1) * 64;
  const int quad = lane >> 4;
  const int l15  = lane & 15;
  const int xorv = l15 & 7;

  #pragma unroll 1
  for (int tap = tap0; tap < tap1; ++tap) {
    if (!kdv[tap / 9]) continue;       // whole-tile-zero depth tap: exact skip
    const int kd = tap / 9; const int rem = tap - kd * 9;
    const int kh = rem / 3; const int kw = rem - kh * 3;
    const int tapA = (((kd * 16) + kh) * 16 + kw) * CIN * 2;
    const int tapB = tap * COUT * CIN * 2;
    #pragma unroll 1
    for (int c0 = 0; c0 < CIN; c0 += 64) {
      const int cb = c0 * 2;
      __syncthreads();
      #pragma unroll
      for (int i = 0; i < 4; ++i)
        async_ld16(Pb + (aoff[i] + tapA + cb), (char*)lA + (i * 256 + tid) * 16);
      #pragma unroll
      for (int i = 0; i < 4; ++i)
        async_ld16(Wb + (boff[i] + tapB + cb), (char*)lB + (i * 256 + tid) * 16);
      __syncthreads();
      #pragma unroll
      for (int ks = 0; ks < 2; ++ks) {
        short8 a[4], b[4];
        #pragma unroll
        for (int i = 0; i < 4; ++i)
          a[i] = *(const short8*)(lA + (wm + i * 16 + l15) * 64 + ((ks * 4 + quad) ^ xorv) * 8);
        #pragma unroll
        for (int j = 0; j < 4; ++j)
          b[j] = *(const short8*)(lB + (wn + j * 16 + l15) * 64 + ((ks * 4 + quad) ^ xorv) * 8);
        #pragma unroll
        for (int i = 0; i < 4; ++i)
          #pragma unroll
          for (int j = 0; j < 4; ++j)
            acc[i][j] = __builtin_amdgcn_mfma_f32_16x16x32_bf16(a[i], b[j], acc[i][j], 0, 0, 0);
      }
    }
  }

  // Epilogue: C/D layout col=lane&15, row=quad*4+reg. Raw bf16 partials.
  // Cells with zero valid taps still write acc==0 (required: reduce sums all).
  #pragma unroll
  for (int j = 0; j < 4; ++j) {
    const int o = n0 + wn + j * 16 + l15;
    #pragma unroll
    for (int i = 0; i < 4; ++i) {
      #pragma unroll
      for (int r = 0; r < 4; ++r) {
        int m = m0 + wm + i * 16 + quad * 4 + r;
        partOut[(size_t)m * COUT + o] = f2bf(acc[i][j][r]);
      }
    }
  }
}

// ---------------------------------------------------------------------------
// reduce1: sum 4 bf16 partial slices (2 in part, 2 in alt) + bias, relu, cast
// bf16, scatter into padded P2 [8][6][16][16][1024] (interior; halo zeroed).
// ---------------------------------------------------------------------------
__global__ void reduce_conv1(const unsigned short* __restrict__ part,
                             const unsigned short* __restrict__ alt,
                             const float* __restrict__ bias,
                             unsigned short* __restrict__ P2) {
  const int idx = blockIdx.x * 256 + threadIdx.x;
  const int m  = idx >> 8;
  const int o4 = (idx & 255) * 4;
  const size_t base = (size_t)m * 1024 + o4;
  const size_t ss = (size_t)M_TOT * 1024;
  ushort4v p0 = *(const ushort4v*)(part + base);
  ushort4v p1 = *(const ushort4v*)(part + ss + base);
  ushort4v p2 = *(const ushort4v*)(alt + base);
  ushort4v p3 = *(const ushort4v*)(alt + ss + base);
  ushort4v out;
  #pragma unroll
  for (int k = 0; k < 4; ++k) {
    float v = bf2f(p0[k]) + bf2f(p1[k]) + bf2f(p2[k]) + bf2f(p3[k]) + bias[o4 + k];
    out[k] = f2bf(v > 0.f ? v : 0.f);
  }
  int t = m / 784;  int r2 = m - t * 784;
  int d = r2 / 196; int r3 = r2 - d * 196;
  int h = r3 / 14;  int w = r3 - h * 14;
  size_t didx = (size_t)(((t * 6 + d + 1) * 16 + (h + 1)) * 16 + (w + 1)) * 1024 + o4;
  *(ushort4v*)(P2 + didx) = out;
}

// ---------------------------------------------------------------------------
// reduce2: sum 8 bf16 partial slices (4 in part, 4 in alt) + bias, relu,
// cast bf16 -> h2 [6272][512].
// ---------------------------------------------------------------------------
__global__ void reduce_conv2(const unsigned short* __restrict__ part,
                             const unsigned short* __restrict__ alt,
                             const float* __restrict__ bias,
                             unsigned short* __restrict__ h2) {
  const int idx = blockIdx.x * 256 + threadIdx.x;
  const int m  = idx >> 7;
  const int o4 = (idx & 127) * 4;
  const size_t base = (size_t)m * 512 + o4;
  const size_t ss = (size_t)M_TOT * 512;
  float v[4];
  #pragma unroll
  for (int k = 0; k < 4; ++k) v[k] = bias[o4 + k];
  #pragma unroll
  for (int s = 0; s < 4; ++s) {
    ushort4v pa = *(const ushort4v*)(part + s * ss + base);
    ushort4v pb = *(const ushort4v*)(alt + s * ss + base);
    #pragma unroll
    for (int k = 0; k < 4; ++k) v[k] += bf2f(pa[k]) + bf2f(pb[k]);
  }
  ushort4v out;
  #pragma unroll
  for (int k = 0; k < 4; ++k) out[k] = f2bf(v[k] > 0.f ? v[k] : 0.f);
  *(ushort4v*)(h2 + base) = out;
}

// ---------------------------------------------------------------------------
// Max-pool, two-stage. h2 bf16 >= 0 -> bit pattern monotone -> max raw ushorts.
// ---------------------------------------------------------------------------
__global__ void pool1(const unsigned short* __restrict__ h2,
                      unsigned short* __restrict__ partial) {
  const int t = blockIdx.x / 28, ch = blockIdx.x % 28, o = threadIdx.x;
  const unsigned short* src = h2 + ((size_t)t * 784 + ch * 28) * 512 + o;
  unsigned short m = 0;
  #pragma unroll 4
  for (int i = 0; i < 28; ++i) { unsigned short v = src[(size_t)i * 512]; m = v > m ? v : m; }
  partial[((size_t)t * 28 + ch) * 512 + o] = m;
}

__global__ void pool2(const unsigned short* __restrict__ partial, float* __restrict__ pooled) {
  const int t = blockIdx.x, o = threadIdx.x;
  const unsigned short* src = partial + (size_t)t * 28 * 512 + o;
  unsigned short m = 0;
  #pragma unroll 4
  for (int i = 0; i < 28; ++i) { unsigned short v = src[(size_t)i * 512]; m = v > m ? v : m; }
  pooled[t * 512 + o] = bf2f(m);
}

// ---------------------------------------------------------------------------
// Tiny MLP, fp32. Block per t, 512 threads.
// ---------------------------------------------------------------------------
__global__ void mlp_kernel(const float* __restrict__ pooled,
                           const float* __restrict__ w1, const float* __restrict__ b1,
                           const float* __restrict__ w2, const float* __restrict__ b2,
                           const float* __restrict__ w3, const float* __restrict__ b3,
                           float* __restrict__ out) {
  const int t = blockIdx.x, j = threadIdx.x;
  __shared__ float xa[512], xb[512];
  xa[j] = pooled[t * 512 + j];
  __syncthreads();
  {
    const float4* wr = (const float4*)(w1 + (size_t)j * 512);
    float s = b1[j];
    #pragma unroll 4
    for (int k = 0; k < 128; ++k) {
      float4 wv = wr[k];
      s += wv.x * xa[4*k] + wv.y * xa[4*k+1] + wv.z * xa[4*k+2] + wv.w * xa[4*k+3];
    }
    xb[j] = fmaxf(s, 0.f);
  }
  __syncthreads();
  {
    const float4* wr = (const float4*)(w2 + (size_t)j * 512);
    float s = b2[j];
    #pragma unroll 4
    for (int k = 0; k < 128; ++k) {
      float4 wv = wr[k];
      s += wv.x * xb[4*k] + wv.y * xb[4*k+1] + wv.z * xb[4*k+2] + wv.w * xb[4*k+3];
    }
    xa[j] = fmaxf(s, 0.f);
  }
  __syncthreads();
  if (j < 128) {
    const float4* wr = (const float4*)(w3 + (size_t)j * 512);
    float s = b3[j];
    #pragma unroll 4
    for (int k = 0; k < 128; ++k) {
      float4 wv = wr[k];
      s += wv.x * xa[4*k] + wv.y * xa[4*k+1] + wv.z * xa[4*k+2] + wv.w * xa[4*k+3];
    }
    out[t * 128 + j] = fmaxf(s, 0.f);
  }
}

// ---------------------------------------------------------------------------
// Workspace layout (bytes) — total ~142.5 MB:
//   P1/P2 (aliased) @ 0          : 8*6*16*16*1024*2 = 25,165,824
//   W1t             @ 25165824   : 27*1024*1024*2   = 56,623,104  (also conv2 alt slices)
//   W2t             @ 81788928   : 27*512*1024*2    = 28,311,552  (also conv1 alt slices)
//   part            @ 110100480  : 25,690,112  (conv1 slices 0-1 / conv2 slices 0-3)
//   h2 bf16         @ 135790592  : 6,422,528
//   pooled          @ 142213120  : 16,384
//   pool partial    @ 142229504  : 229,376
//   tab1            @ 142458880  : 8*196*2 = 3,136
//   tab2            @ 142462016  : 3,136
// Region lifetime plan: conv1's alt slices use the W2t region, so wtrans2 runs
// AFTER reduce_conv1. conv2's alt slices use the W1t region (dead after conv1).
// ---------------------------------------------------------------------------
extern "C" void kernel_launch(void* const* d_in, const int* in_sizes, int n_in,
                              void* d_out, int out_size, void* d_ws, size_t ws_size,
                              hipStream_t stream) {
  const float* videos = (const float*)d_in[0];
  const float* c1w = (const float*)d_in[1];
  const float* c1b = (const float*)d_in[2];
  const float* c2w = (const float*)d_in[3];
  const float* c2b = (const float*)d_in[4];
  const float* l1w = (const float*)d_in[5];
  const float* l1b = (const float*)d_in[6];
  const float* l2w = (const float*)d_in[7];
  const float* l2b = (const float*)d_in[8];
  const float* l3w = (const float*)d_in[9];
  const float* l3b = (const float*)d_in[10];

  char* ws = (char*)d_ws;
  unsigned short* P12  = (unsigned short*)(ws);               // P1, later P2
  unsigned short* W1t  = (unsigned short*)(ws + 25165824);    // + conv2 alt slices
  unsigned short* W2t  = (unsigned short*)(ws + 81788928);    // + conv1 alt slices
  unsigned short* part = (unsigned short*)(ws + 110100480);
  unsigned short* h2   = (unsigned short*)(ws + 135790592);
  float* pooled        = (float*)(ws + 142213120);
  unsigned short* ppart = (unsigned short*)(ws + 142229504);
  unsigned short* tab1 = (unsigned short*)(ws + 142458880);
  unsigned short* tab2 = (unsigned short*)(ws + 142462016);
  float* out = (float*)d_out;

  // Schedule tables (device-built; no H2D memcpys).
  make_sched<<<1, 64, 0, stream>>>(tab1, tab2);

  // Zero the padded activation buffer (halo + unused windows must be 0).
  hipMemsetAsync(ws, 0, 25165824, stream);

  wtrans<<<4096, 256, 0, stream>>>(c1w, W1t, 1024 * 1024);
  build_P1<<<dim3(8, 16), 256, 0, stream>>>(videos, P12);

  // conv1: SLICES=4; slices 0-1 -> part, 2-3 -> W2t region (wtrans2 not yet run).
  conv_gemm<1024, 1024, 4, true ><<<8 * MAXB, 256, 0, stream>>>(P12, W1t, tab1, part, W2t);
  reduce_conv1<<<6272, 256, 0, stream>>>(part, W2t, c1b, P12);

  // Now W2t region is free: build conv2 weights, then conv2 (alt slices in W1t).
  wtrans<<<2048, 256, 0, stream>>>(c2w, W2t, 512 * 1024);
  conv_gemm<1024, 512, 8, false><<<8 * MAXB, 256, 0, stream>>>(P12, W2t, tab2, part, W1t);
  reduce_conv2<<<3136, 256, 0, stream>>>(part, W1t, c2b, h2);

  pool1<<<224, 512, 0, stream>>>(h2, ppart);
  pool2<<<8, 512, 0, stream>>>(ppart, pooled);
  mlp_kernel<<<8, 512, 0, stream>>>(pooled, l1w, l1b, l2w, l2b, l3w, l3b, out);
}

// Round 8
// 960.514 us; speedup vs baseline: 3.3701x; 3.3701x over previous
//
#include <hip/hip_runtime.h>

typedef __attribute__((ext_vector_type(8))) short short8;
typedef __attribute__((ext_vector_type(4))) float floatx4;
typedef __attribute__((ext_vector_type(4))) unsigned short ushort4v;

#define DEV __device__ __forceinline__

constexpr int M_TOT = 6272;   // 8 * 784 output positions
constexpr int MAXB  = 196;    // blocks per XCD bin = 1568/8 exactly

DEV void async_ld16(const void* g, void* l) {
  __builtin_amdgcn_global_load_lds(
      (const __attribute__((address_space(1))) unsigned int*)g,
      (__attribute__((address_space(3))) unsigned int*)l,
      16, 0, 0);
}

DEV unsigned short f2bf(float x) {
  union { float f; unsigned int u; } v; v.f = x;
  unsigned int u = v.u;
  u += 0x7FFFu + ((u >> 16) & 1u);   // round-to-nearest-even
  return (unsigned short)(u >> 16);
}

DEV float bf2f(unsigned short s) {
  union { unsigned int u; float f; } v; v.u = ((unsigned int)s) << 16;
  return v.f;
}

// ---------------------------------------------------------------------------
// COMPILE-TIME schedule builder (R8: R7 ran this on 1 GPU lane with a
// scratch-spilled 6 KB array -> 2430 µs, 75% of total runtime. The schedule
// depends only on tile geometry, so it is a constexpr -> __constant__ table;
// zero runtime cost). Logic identical to R7: 1568 cells = 49 x-tiles * 32 g
// (g = n*S + z), x-major walk, work-prefix target bin, capacity-constrained
// to 196/bin with nearest-non-full probing (bijective, nothing dropped).
// x-contiguous slabs keep R4's XCD-L2 locality + R5's work balance.
// ---------------------------------------------------------------------------
struct SchedT { unsigned short t1[8 * MAXB]; unsigned short t2[8 * MAXB]; };

constexpr SchedT build_sched() {
  SchedT st{};
  for (int conv = 0; conv < 2; ++conv) {
    const int S = conv ? 8 : 4;
    unsigned short* tab = conv ? st.t2 : st.t1;
    long total = 0;
    int w[1568] = {};
    for (int x = 0; x < 49; ++x) {
      const int m0 = x * 128;
      const int c1 = m0 / 196, c2 = (m0 + 127) / 196;
      bool kdv[3] = {};
      for (int kd = 0; kd < 3; ++kd) {
        bool v = false;
        for (int ci = 0; ci < 2; ++ci) {
          int c = ci ? c2 : c1;
          if (ci && c2 == c1) continue;
          int t = c >> 2, d = c & 3, s = d + kd;
          bool ok = (s >= 1) && (s <= 4);
          if (conv == 0) ok = ok && (s >= 5 - t);   // conv1 frame condition
          v = v || ok;
        }
        kdv[kd] = v;
      }
      for (int g = 0; g < 32; ++g) {
        int z = g % S;
        int t0 = (27 * z) / S, t1 = (27 * (z + 1)) / S, cnt = 0;
        for (int tap = t0; tap < t1; ++tap) if (kdv[tap / 9]) ++cnt;
        w[x * 32 + g] = cnt * 16 + 3;   // 16 K-steps per tap + per-block overhead
        total += w[x * 32 + g];
      }
    }
    long cum = 0;
    int count[8] = {};
    for (int c = 0; c < 1568; ++c) {
      int b = (int)(((cum + w[c] / 2) * 8) / total);
      if (b > 7) b = 7;
      if (count[b] >= MAXB) {                 // capacity probe
        int nb = -1;
        for (int d = b + 1; d < 8 && nb < 0; ++d) if (count[d] < MAXB) nb = d;
        for (int d = b - 1; d >= 0 && nb < 0; --d) if (count[d] < MAXB) nb = d;
        b = nb;                               // always found: capacity == cells
      }
      tab[b * MAXB + count[b]++] = (unsigned short)c;
      cum += w[c];
    }
  }
  return st;
}

__constant__ SchedT g_sched = build_sched();

// ---------------------------------------------------------------------------
// Weight transform: conv_w fp32 [O][C][3][3][3] -> bf16 [tap][o][c]  (B^T).
// LDS transpose — coalesced reads and writes.
// ---------------------------------------------------------------------------
__global__ void wtrans(const float* __restrict__ w, unsigned short* __restrict__ wt,
                       int total /* = O*C, multiple of 256 */) {
  __shared__ unsigned short l[256 * 27];
  const int tid  = threadIdx.x;
  const int base = blockIdx.x * 256;
  #pragma unroll 1
  for (int j = tid; j < 256 * 27; j += 256)
    l[j] = f2bf(w[(size_t)base * 27 + j]);
  __syncthreads();
  #pragma unroll 1
  for (int tap = 0; tap < 27; ++tap)
    wt[(size_t)tap * total + base + tid] = l[tid * 27 + tap];
}

// ---------------------------------------------------------------------------
// Build P1: videos fp32 [8][1024][14][14] -> P1 bf16 [t=8][s=6][16][16][1024]
// P1[t][s][h+1][w+1][c] = videos[t-5+s][c][h][w] for s in 1..4 (else zero).
// ---------------------------------------------------------------------------
__global__ void build_P1(const float* __restrict__ videos, unsigned short* __restrict__ P1) {
  const int f  = blockIdx.x;
  const int c0 = blockIdx.y * 64;
  const int tid = threadIdx.x;
  __shared__ unsigned short tile[64][196];

  #pragma unroll 1
  for (int it = 0; it < 49; ++it) {       // 49*256 = 64*196 exactly
    int idx = it * 256 + tid;
    int c = idx / 196, r = idx - c * 196;
    tile[c][r] = f2bf(videos[(size_t)(f * 1024 + c0 + c) * 196 + r]);
  }
  __syncthreads();

  const int c   = tid & 63;
  const int hwq = tid >> 6;
  #pragma unroll 1
  for (int s = 1; s <= 4; ++s) {
    int t = f + 5 - s;
    if (t > 7) continue;
    unsigned short* dst = P1 + (size_t)(t * 6 + s) * 256 * 1024 + (size_t)c0;
    #pragma unroll 1
    for (int it = 0; it < 49; ++it) {
      int hw = it * 4 + hwq;
      int h = hw / 14, w = hw - h * 14;
      dst[(size_t)((h + 1) * 16 + (w + 1)) * 1024 + c] = tile[c][hw];
    }
  }
}

// ---------------------------------------------------------------------------
// Implicit-GEMM conv, split-K over taps. 128x128 tile, BK=64, global_load_lds
// x16 with XOR-swizzled segment fetch (zero LDS bank conflicts — R2),
// mfma_f32_16x16x32_bf16, structural tap skipping (R5, exact), constexpr
// schedule-table block mapping (R8). Writes bf16 partial sums; slice z goes
// to part0 (z<S/2) or alt0 (z>=S/2, dead weight region — see kernel_launch).
// A: padded input P [8][6][16][16][CIN] bf16;  B: Wt [27][COUT][CIN] bf16.
// Grid: 8*MAXB slots; slot -> tab[(slot&7)*MAXB + (slot>>3)] (all valid).
// ---------------------------------------------------------------------------
template <int CIN, int COUT, int SLICES, bool TCOND, int CONV>
__global__ __launch_bounds__(256) void conv_gemm(
    const unsigned short* __restrict__ P,
    const unsigned short* __restrict__ Wt,
    unsigned short* __restrict__ part0,
    unsigned short* __restrict__ alt0)
{
  __shared__ short lA[128 * 64];
  __shared__ short lB[128 * 64];
  const unsigned short* tab = CONV ? g_sched.t2 : g_sched.t1;
  const int slot = blockIdx.x;
  const int cellv = tab[(slot & 7) * MAXB + (slot >> 3)];

  const int tid  = threadIdx.x;
  const int wave = tid >> 6;
  const int lane = tid & 63;

  const int x = cellv >> 5;              // 0..48
  const int g = cellv & 31;              // n*SLICES + z
  const int m0 = x * 128;
  const int n0 = (g / SLICES) * 128;
  const int z  = g % SLICES;

  const int tap0 = (27 * z) / SLICES;
  const int tap1 = (27 * (z + 1)) / SLICES;
  const size_t SS = (size_t)M_TOT * COUT;
  unsigned short* partOut = (z < SLICES / 2)
      ? part0 + (size_t)z * SS
      : alt0 + (size_t)(z - SLICES / 2) * SS;

  // Tile-level depth-tap validity (exact skip of all-zero slices).
  bool kdv[3];
  {
    const int c1 = m0 / 196, c2 = (m0 + 127) / 196;
    #pragma unroll
    for (int kd = 0; kd < 3; ++kd) {
      bool v = false;
      #pragma unroll
      for (int ci = 0; ci < 2; ++ci) {
        int c = ci ? c2 : c1;
        if (ci && c2 == c1) continue;
        int t = c >> 2, d = c & 3, s = d + kd;
        bool ok = (s >= 1) && (s <= 4);
        if (TCOND) ok = ok && (s >= 5 - t);
        v = v || ok;
      }
      kdv[kd] = v;
    }
  }

  // Staging: LDS segment s_i = i*256+tid (16B units); row r = s_i>>3.
  // XOR swizzle: fetch global segment (tid&7)^(r&7).
  const int rb   = tid >> 3;
  const int segb = (((tid & 7) ^ (rb & 7)) * 16);
  int aoff[4], boff[4];
  #pragma unroll
  for (int i = 0; i < 4; ++i) {
    int r = i * 32 + rb;
    int m = m0 + r;
    int t = m / 784;  int r2 = m - t * 784;
    int d = r2 / 196; int r3 = r2 - d * 196;
    int h = r3 / 14;  int w = r3 - h * 14;
    aoff[i] = ((((t * 6 + d) * 16 + h) * 16 + w) * CIN) * 2 + segb;  // tap-separable
    boff[i] = ((n0 + r) * CIN) * 2 + segb;
  }

  floatx4 acc[4][4];
  const floatx4 zero = {0.f, 0.f, 0.f, 0.f};
  #pragma unroll
  for (int i = 0; i < 4; ++i)
    #pragma unroll
    for (int j = 0; j < 4; ++j) acc[i][j] = zero;

  const char* Pb = (const char*)P;
  const char* Wb = (const char*)Wt;
  const int wm = (wave >> 1) * 64;
  const int wn = (wave & 1) * 64;
  const int quad = lane >> 4;
  const int l15  = lane & 15;
  const int xorv = l15 & 7;

  #pragma unroll 1
  for (int tap = tap0; tap < tap1; ++tap) {
    if (!kdv[tap / 9]) continue;       // whole-tile-zero depth tap: exact skip
    const int kd = tap / 9; const int rem = tap - kd * 9;
    const int kh = rem / 3; const int kw = rem - kh * 3;
    const int tapA = (((kd * 16) + kh) * 16 + kw) * CIN * 2;
    const int tapB = tap * COUT * CIN * 2;
    #pragma unroll 1
    for (int c0 = 0; c0 < CIN; c0 += 64) {
      const int cb = c0 * 2;
      __syncthreads();
      #pragma unroll
      for (int i = 0; i < 4; ++i)
        async_ld16(Pb + (aoff[i] + tapA + cb), (char*)lA + (i * 256 + tid) * 16);
      #pragma unroll
      for (int i = 0; i < 4; ++i)
        async_ld16(Wb + (boff[i] + tapB + cb), (char*)lB + (i * 256 + tid) * 16);
      __syncthreads();
      #pragma unroll
      for (int ks = 0; ks < 2; ++ks) {
        short8 a[4], b[4];
        #pragma unroll
        for (int i = 0; i < 4; ++i)
          a[i] = *(const short8*)(lA + (wm + i * 16 + l15) * 64 + ((ks * 4 + quad) ^ xorv) * 8);
        #pragma unroll
        for (int j = 0; j < 4; ++j)
          b[j] = *(const short8*)(lB + (wn + j * 16 + l15) * 64 + ((ks * 4 + quad) ^ xorv) * 8);
        #pragma unroll
        for (int i = 0; i < 4; ++i)
          #pragma unroll
          for (int j = 0; j < 4; ++j)
            acc[i][j] = __builtin_amdgcn_mfma_f32_16x16x32_bf16(a[i], b[j], acc[i][j], 0, 0, 0);
      }
    }
  }

  // Epilogue: C/D layout col=lane&15, row=quad*4+reg. Raw bf16 partials.
  // Cells with zero valid taps still write acc==0 (required: reduce sums all).
  #pragma unroll
  for (int j = 0; j < 4; ++j) {
    const int o = n0 + wn + j * 16 + l15;
    #pragma unroll
    for (int i = 0; i < 4; ++i) {
      #pragma unroll
      for (int r = 0; r < 4; ++r) {
        int m = m0 + wm + i * 16 + quad * 4 + r;
        partOut[(size_t)m * COUT + o] = f2bf(acc[i][j][r]);
      }
    }
  }
}

// ---------------------------------------------------------------------------
// reduce1: sum 4 bf16 partial slices (2 in part, 2 in alt) + bias, relu, cast
// bf16, scatter into padded P2 [8][6][16][16][1024] (interior; halo zeroed).
// ---------------------------------------------------------------------------
__global__ void reduce_conv1(const unsigned short* __restrict__ part,
                             const unsigned short* __restrict__ alt,
                             const float* __restrict__ bias,
                             unsigned short* __restrict__ P2) {
  const int idx = blockIdx.x * 256 + threadIdx.x;
  const int m  = idx >> 8;
  const int o4 = (idx & 255) * 4;
  const size_t base = (size_t)m * 1024 + o4;
  const size_t ss = (size_t)M_TOT * 1024;
  ushort4v p0 = *(const ushort4v*)(part + base);
  ushort4v p1 = *(const ushort4v*)(part + ss + base);
  ushort4v p2 = *(const ushort4v*)(alt + base);
  ushort4v p3 = *(const ushort4v*)(alt + ss + base);
  ushort4v out;
  #pragma unroll
  for (int k = 0; k < 4; ++k) {
    float v = bf2f(p0[k]) + bf2f(p1[k]) + bf2f(p2[k]) + bf2f(p3[k]) + bias[o4 + k];
    out[k] = f2bf(v > 0.f ? v : 0.f);
  }
  int t = m / 784;  int r2 = m - t * 784;
  int d = r2 / 196; int r3 = r2 - d * 196;
  int h = r3 / 14;  int w = r3 - h * 14;
  size_t didx = (size_t)(((t * 6 + d + 1) * 16 + (h + 1)) * 16 + (w + 1)) * 1024 + o4;
  *(ushort4v*)(P2 + didx) = out;
}

// ---------------------------------------------------------------------------
// reduce2: sum 8 bf16 partial slices (4 in part, 4 in alt) + bias, relu,
// cast bf16 -> h2 [6272][512].
// ---------------------------------------------------------------------------
__global__ void reduce_conv2(const unsigned short* __restrict__ part,
                             const unsigned short* __restrict__ alt,
                             const float* __restrict__ bias,
                             unsigned short* __restrict__ h2) {
  const int idx = blockIdx.x * 256 + threadIdx.x;
  const int m  = idx >> 7;
  const int o4 = (idx & 127) * 4;
  const size_t base = (size_t)m * 512 + o4;
  const size_t ss = (size_t)M_TOT * 512;
  float v[4];
  #pragma unroll
  for (int k = 0; k < 4; ++k) v[k] = bias[o4 + k];
  #pragma unroll
  for (int s = 0; s < 4; ++s) {
    ushort4v pa = *(const ushort4v*)(part + s * ss + base);
    ushort4v pb = *(const ushort4v*)(alt + s * ss + base);
    #pragma unroll
    for (int k = 0; k < 4; ++k) v[k] += bf2f(pa[k]) + bf2f(pb[k]);
  }
  ushort4v out;
  #pragma unroll
  for (int k = 0; k < 4; ++k) out[k] = f2bf(v[k] > 0.f ? v[k] : 0.f);
  *(ushort4v*)(h2 + base) = out;
}

// ---------------------------------------------------------------------------
// Max-pool, two-stage. h2 bf16 >= 0 -> bit pattern monotone -> max raw ushorts.
// ---------------------------------------------------------------------------
__global__ void pool1(const unsigned short* __restrict__ h2,
                      unsigned short* __restrict__ partial) {
  const int t = blockIdx.x / 28, ch = blockIdx.x % 28, o = threadIdx.x;
  const unsigned short* src = h2 + ((size_t)t * 784 + ch * 28) * 512 + o;
  unsigned short m = 0;
  #pragma unroll 4
  for (int i = 0; i < 28; ++i) { unsigned short v = src[(size_t)i * 512]; m = v > m ? v : m; }
  partial[((size_t)t * 28 + ch) * 512 + o] = m;
}

__global__ void pool2(const unsigned short* __restrict__ partial, float* __restrict__ pooled) {
  const int t = blockIdx.x, o = threadIdx.x;
  const unsigned short* src = partial + (size_t)t * 28 * 512 + o;
  unsigned short m = 0;
  #pragma unroll 4
  for (int i = 0; i < 28; ++i) { unsigned short v = src[(size_t)i * 512]; m = v > m ? v : m; }
  pooled[t * 512 + o] = bf2f(m);
}

// ---------------------------------------------------------------------------
// Tiny MLP, fp32. Block per t, 512 threads.
// ---------------------------------------------------------------------------
__global__ void mlp_kernel(const float* __restrict__ pooled,
                           const float* __restrict__ w1, const float* __restrict__ b1,
                           const float* __restrict__ w2, const float* __restrict__ b2,
                           const float* __restrict__ w3, const float* __restrict__ b3,
                           float* __restrict__ out) {
  const int t = blockIdx.x, j = threadIdx.x;
  __shared__ float xa[512], xb[512];
  xa[j] = pooled[t * 512 + j];
  __syncthreads();
  {
    const float4* wr = (const float4*)(w1 + (size_t)j * 512);
    float s = b1[j];
    #pragma unroll 4
    for (int k = 0; k < 128; ++k) {
      float4 wv = wr[k];
      s += wv.x * xa[4*k] + wv.y * xa[4*k+1] + wv.z * xa[4*k+2] + wv.w * xa[4*k+3];
    }
    xb[j] = fmaxf(s, 0.f);
  }
  __syncthreads();
  {
    const float4* wr = (const float4*)(w2 + (size_t)j * 512);
    float s = b2[j];
    #pragma unroll 4
    for (int k = 0; k < 128; ++k) {
      float4 wv = wr[k];
      s += wv.x * xb[4*k] + wv.y * xb[4*k+1] + wv.z * xb[4*k+2] + wv.w * xb[4*k+3];
    }
    xa[j] = fmaxf(s, 0.f);
  }
  __syncthreads();
  if (j < 128) {
    const float4* wr = (const float4*)(w3 + (size_t)j * 512);
    float s = b3[j];
    #pragma unroll 4
    for (int k = 0; k < 128; ++k) {
      float4 wv = wr[k];
      s += wv.x * xa[4*k] + wv.y * xa[4*k+1] + wv.z * xa[4*k+2] + wv.w * xa[4*k+3];
    }
    out[t * 128 + j] = fmaxf(s, 0.f);
  }
}

// ---------------------------------------------------------------------------
// Workspace layout (bytes) — total ~142.4 MB:
//   P1/P2 (aliased) @ 0          : 8*6*16*16*1024*2 = 25,165,824
//   W1t             @ 25165824   : 27*1024*1024*2   = 56,623,104  (also conv2 alt slices)
//   W2t             @ 81788928   : 27*512*1024*2    = 28,311,552  (also conv1 alt slices)
//   part            @ 110100480  : 25,690,112  (conv1 slices 0-1 / conv2 slices 0-3)
//   h2 bf16         @ 135790592  : 6,422,528
//   pooled          @ 142213120  : 16,384
//   pool partial    @ 142229504  : 229,376
// Region lifetime plan: conv1's alt slices use the W2t region, so wtrans2 runs
// AFTER reduce_conv1. conv2's alt slices use the W1t region (dead after conv1).
// ---------------------------------------------------------------------------
extern "C" void kernel_launch(void* const* d_in, const int* in_sizes, int n_in,
                              void* d_out, int out_size, void* d_ws, size_t ws_size,
                              hipStream_t stream) {
  const float* videos = (const float*)d_in[0];
  const float* c1w = (const float*)d_in[1];
  const float* c1b = (const float*)d_in[2];
  const float* c2w = (const float*)d_in[3];
  const float* c2b = (const float*)d_in[4];
  const float* l1w = (const float*)d_in[5];
  const float* l1b = (const float*)d_in[6];
  const float* l2w = (const float*)d_in[7];
  const float* l2b = (const float*)d_in[8];
  const float* l3w = (const float*)d_in[9];
  const float* l3b = (const float*)d_in[10];

  char* ws = (char*)d_ws;
  unsigned short* P12  = (unsigned short*)(ws);               // P1, later P2
  unsigned short* W1t  = (unsigned short*)(ws + 25165824);    // + conv2 alt slices
  unsigned short* W2t  = (unsigned short*)(ws + 81788928);    // + conv1 alt slices
  unsigned short* part = (unsigned short*)(ws + 110100480);
  unsigned short* h2   = (unsigned short*)(ws + 135790592);
  float* pooled        = (float*)(ws + 142213120);
  unsigned short* ppart = (unsigned short*)(ws + 142229504);
  float* out = (float*)d_out;

  // Zero the padded activation buffer (halo + unused windows must be 0).
  hipMemsetAsync(ws, 0, 25165824, stream);

  wtrans<<<4096, 256, 0, stream>>>(c1w, W1t, 1024 * 1024);
  build_P1<<<dim3(8, 16), 256, 0, stream>>>(videos, P12);

  // conv1: SLICES=4; slices 0-1 -> part, 2-3 -> W2t region (wtrans2 not yet run).
  conv_gemm<1024, 1024, 4, true, 0><<<8 * MAXB, 256, 0, stream>>>(P12, W1t, part, W2t);
  reduce_conv1<<<6272, 256, 0, stream>>>(part, W2t, c1b, P12);

  // Now W2t region is free: build conv2 weights, then conv2 (alt slices in W1t).
  wtrans<<<2048, 256, 0, stream>>>(c2w, W2t, 512 * 1024);
  conv_gemm<1024, 512, 8, false, 1><<<8 * MAXB, 256, 0, stream>>>(P12, W2t, part, W1t);
  reduce_conv2<<<3136, 256, 0, stream>>>(part, W1t, c2b, h2);

  pool1<<<224, 512, 0, stream>>>(h2, ppart);
  pool2<<<8, 512, 0, stream>>>(ppart, pooled);
  mlp_kernel<<<8, 512, 0, stream>>>(pooled, l1w, l1b, l2w, l2b, l3w, l3b, out);
}